// Round 1
// baseline (67.633 us; speedup 1.0000x reference)
//
#include <hip/hip_runtime.h>

// BaseGraph (NRI-style node2edge/edge2node) on the complete graph minus
// diagonal, with normalize-by-N:
//   out[b,n,0:D]   = (N-1)/N * x[b,n,:]
//   out[b,n,D:2D]  = (sum_j x[b,j,:] - x[b,n,:]) / N
// The receivers/senders index arrays (d_in[1], d_in[2]) describe exactly this
// fixed complete graph (np.where(ones - eye)), so the closed form above is
// the whole computation. O(B*N*D) instead of O(B*E*D).

constexpr int BATCH = 8;
constexpr int NNODE = 256;
constexpr int DFEAT = 128;

// Kernel 1: S[b][d] = sum_n x[b][n][d].  grid = BATCH, block = DFEAT.
__global__ void __launch_bounds__(DFEAT) node_sum_kernel(
    const float* __restrict__ x, float* __restrict__ S) {
  const int b = blockIdx.x;
  const int d = threadIdx.x;
  const float* xb = x + (size_t)b * NNODE * DFEAT + d;
  float acc = 0.0f;
#pragma unroll 8
  for (int n = 0; n < NNODE; ++n) {
    acc += xb[(size_t)n * DFEAT];
  }
  S[b * DFEAT + d] = acc;
}

// Kernel 2: one thread per float4 of x.  Writes both output halves.
// out layout: [B, N, 2*D], row-major.
__global__ void __launch_bounds__(256) edge2node_kernel(
    const float* __restrict__ x, const float* __restrict__ S,
    float* __restrict__ out) {
  const int tid = blockIdx.x * 256 + threadIdx.x;  // 0 .. B*N*D/4 - 1
  const int dv = tid & (DFEAT / 4 - 1);            // float4 index within row
  const int bn = tid >> 5;                         // DFEAT/4 == 32
  const int b = bn >> 8;                           // NNODE == 256

  const float4 x4 = reinterpret_cast<const float4*>(x)[tid];
  const float4 s4 =
      reinterpret_cast<const float4*>(S)[b * (DFEAT / 4) + dv];

  constexpr float kRecvScale = (float)(NNODE - 1) / (float)NNODE;  // 255/256
  constexpr float kInvN = 1.0f / (float)NNODE;

  float4 h1, h2;
  h1.x = x4.x * kRecvScale;
  h1.y = x4.y * kRecvScale;
  h1.z = x4.z * kRecvScale;
  h1.w = x4.w * kRecvScale;
  h2.x = (s4.x - x4.x) * kInvN;
  h2.y = (s4.y - x4.y) * kInvN;
  h2.z = (s4.z - x4.z) * kInvN;
  h2.w = (s4.w - x4.w) * kInvN;

  float4* orow = reinterpret_cast<float4*>(out + (size_t)bn * (2 * DFEAT));
  orow[dv] = h1;                  // first half: receiver self-features
  orow[DFEAT / 4 + dv] = h2;      // second half: sum of senders
}

extern "C" void kernel_launch(void* const* d_in, const int* in_sizes, int n_in,
                              void* d_out, int out_size, void* d_ws,
                              size_t ws_size, hipStream_t stream) {
  const float* x = (const float*)d_in[0];
  // d_in[1] (receivers) / d_in[2] (senders) encode the fixed complete graph;
  // not needed at runtime (see header comment).
  float* S = (float*)d_ws;        // BATCH * DFEAT floats = 4 KB scratch
  float* out = (float*)d_out;

  node_sum_kernel<<<BATCH, DFEAT, 0, stream>>>(x, S);

  const int total_vec4 = BATCH * NNODE * DFEAT / 4;  // 65536
  edge2node_kernel<<<total_vec4 / 256, 256, 0, stream>>>(x, S, out);
}

// Round 2
// 58.820 us; speedup vs baseline: 1.1498x; 1.1498x over previous
//
#include <hip/hip_runtime.h>

// BaseGraph (NRI-style node2edge/edge2node) on the complete graph minus
// diagonal, with normalize-by-N:
//   out[b,n,0:D]   = (N-1)/N * x[b,n,:]
//   out[b,n,D:2D]  = (sum_j x[b,j,:] - x[b,n,:]) / N
// receivers/senders (d_in[1], d_in[2]) encode exactly this fixed complete
// graph (np.where(ones - eye)), so the closed form is the whole computation.
// O(B*N*D) instead of O(B*E*D).
//
// R1 -> R2: node_sum had only 16 waves (8 blocks x 128 thr) with a 256-deep
// load loop — pure latency exposure. Now: kernel 1 writes 8 partial sums per
// (batch, feature) from 64 blocks (128 waves, 32-deep loop); kernel 2 folds
// the 8 partials (32 KB table, L1/L2-hot) while doing the float4 streaming.

constexpr int BATCH = 8;
constexpr int NNODE = 256;
constexpr int DFEAT = 128;
constexpr int CHUNKS = 8;                  // node chunks per batch
constexpr int NPC = NNODE / CHUNKS;        // 32 nodes per chunk

// Kernel 1: P[b][c][d] = sum over nodes in chunk c of x[b][n][d].
// grid = BATCH*CHUNKS (64), block = DFEAT (128). No atomics, no init needed.
__global__ void __launch_bounds__(DFEAT) partial_sum_kernel(
    const float* __restrict__ x, float* __restrict__ P) {
  const int b = blockIdx.x >> 3;           // CHUNKS == 8
  const int c = blockIdx.x & (CHUNKS - 1);
  const int d = threadIdx.x;
  const float* xb = x + ((size_t)(b * NNODE + c * NPC)) * DFEAT + d;
  float acc = 0.0f;
#pragma unroll
  for (int i = 0; i < NPC; ++i) {
    acc += xb[(size_t)i * DFEAT];
  }
  P[(b * CHUNKS + c) * DFEAT + d] = acc;
}

// Kernel 2: one thread per float4 of x. Folds the CHUNKS partials into the
// batch sum, then writes both output halves. out layout: [B, N, 2*D].
__global__ void __launch_bounds__(256) edge2node_kernel(
    const float* __restrict__ x, const float* __restrict__ P,
    float* __restrict__ out) {
  const int tid = blockIdx.x * 256 + threadIdx.x;  // 0 .. B*N*D/4 - 1
  const int dv = tid & (DFEAT / 4 - 1);            // float4 index within row
  const int bn = tid >> 5;                         // DFEAT/4 == 32
  const int b = bn >> 8;                           // NNODE == 256

  const float4 x4 = reinterpret_cast<const float4*>(x)[tid];

  // Fold 8 partial float4s (hot in L1: 4 KB per batch).
  const float4* Pb =
      reinterpret_cast<const float4*>(P) + b * (CHUNKS * DFEAT / 4) + dv;
  float4 s4 = Pb[0];
#pragma unroll
  for (int c = 1; c < CHUNKS; ++c) {
    const float4 p = Pb[c * (DFEAT / 4)];
    s4.x += p.x;
    s4.y += p.y;
    s4.z += p.z;
    s4.w += p.w;
  }

  constexpr float kRecvScale = (float)(NNODE - 1) / (float)NNODE;  // 255/256
  constexpr float kInvN = 1.0f / (float)NNODE;

  float4 h1, h2;
  h1.x = x4.x * kRecvScale;
  h1.y = x4.y * kRecvScale;
  h1.z = x4.z * kRecvScale;
  h1.w = x4.w * kRecvScale;
  h2.x = (s4.x - x4.x) * kInvN;
  h2.y = (s4.y - x4.y) * kInvN;
  h2.z = (s4.z - x4.z) * kInvN;
  h2.w = (s4.w - x4.w) * kInvN;

  float4* orow = reinterpret_cast<float4*>(out + (size_t)bn * (2 * DFEAT));
  orow[dv] = h1;                  // first half: receiver self-features
  orow[DFEAT / 4 + dv] = h2;      // second half: sum of senders
}

extern "C" void kernel_launch(void* const* d_in, const int* in_sizes, int n_in,
                              void* d_out, int out_size, void* d_ws,
                              size_t ws_size, hipStream_t stream) {
  const float* x = (const float*)d_in[0];
  // d_in[1] (receivers) / d_in[2] (senders): fixed complete graph; unused.
  float* P = (float*)d_ws;        // BATCH * CHUNKS * DFEAT floats = 32 KB
  float* out = (float*)d_out;

  partial_sum_kernel<<<BATCH * CHUNKS, DFEAT, 0, stream>>>(x, P);

  const int total_vec4 = BATCH * NNODE * DFEAT / 4;  // 65536
  edge2node_kernel<<<total_vec4 / 256, 256, 0, stream>>>(x, P, out);
}